// Round 8
// baseline (214.728 us; speedup 1.0000x reference)
//
#include <hip/hip_runtime.h>
#include <hip/hip_bf16.h>

#define B_SZ 32768
#define K_SZ 10
#define N_SZ 200000
#define D_SZ 128
#define L_SZ 100
#define H_SZ 512

typedef float v2f __attribute__((ext_vector_type(2)));

// One wave (64 lanes) per batch element b.
// b is forced into an SGPR (readfirstlane) so ALL per-b/per-k index and
// feature loads become scalar s_loads (wave-uniform addresses).
// Lane l owns hidden rows h = l + 64*i, i = 0..7 (weights preloaded to regs).
// Gather/output: lane l owns out[b, 2l:2l+2].
//
// Schedule: s_load nb[] -> issue all 10 embed gathers (vector, coalesced)
// -> scalar feature loads -> MLP for all 10 k (paired-sigmoid, 1.5 TRANS/unit)
// -> 10 independent 6-step butterflies (latency overlapped) -> 10 FMAs -> store.
__global__ __launch_bounds__(256) void agg_kernel(
    const int*   __restrict__ nodes,
    const int*   __restrict__ neighs,
    const float* __restrict__ embed,
    const int*   __restrict__ labels,
    const float* __restrict__ distance,
    const float* __restrict__ spectral,
    const float* __restrict__ freq,
    const float* __restrict__ dist_e,
    const float* __restrict__ W1,
    const float* __restrict__ b1,
    const float* __restrict__ W2,
    const float* __restrict__ b2,
    float*       __restrict__ out)
{
    const int lane = threadIdx.x & 63;
    // wave-uniform batch index, provably uniform to the compiler -> SGPR
    const int b = __builtin_amdgcn_readfirstlane(
        (blockIdx.x * 256 + (int)threadIdx.x) >> 6);

    // ---- neighbor indices first (SGPR), then kick off the embed gathers ----
    int nb[K_SZ];
#pragma unroll
    for (int k = 0; k < K_SZ; ++k) nb[k] = neighs[b * K_SZ + k];

    v2f e[K_SZ];
#pragma unroll
    for (int k = 0; k < K_SZ; ++k)
        e[k] = ((const v2f*)(embed + (size_t)nb[k] * D_SZ))[lane];

    // ---- preload MLP weights into registers (invariant across k) ----
    float4 w1r[8];
    float  b1r[8], w2r[8];
#pragma unroll
    for (int i = 0; i < 8; ++i) {
        const int h = lane + 64 * i;
        w1r[i] = ((const float4*)W1)[h];   // W1 row h: 4 contiguous floats
        b1r[i] = b1[h];
        w2r[i] = W2[h];
    }
    float w2s[4];
#pragma unroll
    for (int j = 0; j < 4; ++j) w2s[j] = w2r[2*j] + w2r[2*j+1];
    const float b2v = b2[0];

    // ---- per-b scalar context (SGPR) ----
    const int   node  = nodes[b];
    const int   lab_i = labels[node];
    const float* __restrict__ distRow = distance + (size_t)lab_i * L_SZ;

    float f0[K_SZ], f1[K_SZ], f2[K_SZ], f3[K_SZ];
#pragma unroll
    for (int k = 0; k < K_SZ; ++k) {
        f0[k] = freq[b * K_SZ + k];
        f1[k] = dist_e[b * K_SZ + k];
    }
    int labj[K_SZ];
#pragma unroll
    for (int k = 0; k < K_SZ; ++k) labj[k] = labels[nb[k]];
#pragma unroll
    for (int k = 0; k < K_SZ; ++k) {
        f2[k] = distRow[labj[k]];
        f3[k] = spectral[nb[k]];
    }

    // ---- MLP layer 1+2 partials for ALL k (no cross-lane ops yet) ----
    // Paired sigmoid (exact algebra, 1 v_rcp per 2 hidden units):
    //   w2a*sig(xa) + w2b*sig(xb)
    //     = (w2a + w2b + w2a*ub + w2b*ua) / ((1+ua)(1+ub)),  u = exp(-x)
    float part[K_SZ];
#pragma unroll
    for (int k = 0; k < K_SZ; ++k) {
        float p = 0.f;
#pragma unroll
        for (int j = 0; j < 4; ++j) {
            const float4 wa = w1r[2*j], wb = w1r[2*j+1];
            const float xa = fmaf(wa.x, f0[k], fmaf(wa.y, f1[k],
                             fmaf(wa.z, f2[k], fmaf(wa.w, f3[k], b1r[2*j]))));
            const float xb = fmaf(wb.x, f0[k], fmaf(wb.y, f1[k],
                             fmaf(wb.z, f2[k], fmaf(wb.w, f3[k], b1r[2*j+1]))));
            const float ua = __expf(-xa);
            const float ub = __expf(-xb);
            const float num = fmaf(w2r[2*j], ub, fmaf(w2r[2*j+1], ua, w2s[j]));
            const float den = fmaf(ua, ub, (1.f + ua) + ub);
            p = fmaf(num, __builtin_amdgcn_rcpf(den), p);
        }
        part[k] = p;
    }

    // ---- 10 independent 64-lane butterflies (latency overlaps via ILP) ----
#pragma unroll
    for (int off = 32; off > 0; off >>= 1) {
#pragma unroll
        for (int k = 0; k < K_SZ; ++k)
            part[k] += __shfl_xor(part[k], off, 64);
    }

    // ---- final sigmoid per k + weighted accumulate of prefetched rows ----
    float acc0 = 0.f, acc1 = 0.f;
#pragma unroll
    for (int k = 0; k < K_SZ; ++k) {
        const float imp = __builtin_amdgcn_rcpf(1.f + __expf(-(part[k] + b2v)));
        const float w   = imp * 0.1f;   // 1/K
        acc0 = fmaf(w, e[k].x, acc0);
        acc1 = fmaf(w, e[k].y, acc1);
    }

    v2f r; r.x = acc0; r.y = acc1;
    __builtin_nontemporal_store(r, (v2f*)(out + (size_t)b * D_SZ) + lane);
}

extern "C" void kernel_launch(void* const* d_in, const int* in_sizes, int n_in,
                              void* d_out, int out_size, void* d_ws, size_t ws_size,
                              hipStream_t stream) {
    const int*   nodes    = (const int*)  d_in[0];
    const int*   neighs   = (const int*)  d_in[1];
    const float* embed    = (const float*)d_in[2];
    const int*   labels   = (const int*)  d_in[3];
    const float* distance = (const float*)d_in[4];
    const float* spectral = (const float*)d_in[5];
    const float* freq     = (const float*)d_in[6];
    const float* dist_e   = (const float*)d_in[7];
    const float* W1       = (const float*)d_in[8];
    const float* b1       = (const float*)d_in[9];
    const float* W2       = (const float*)d_in[10];
    const float* b2       = (const float*)d_in[11];
    float* out = (float*)d_out;

    // 1 wave per b: 32768 waves, 4 waves/block -> 8192 blocks
    const int threads = 256;
    const int blocks  = (B_SZ * 64) / threads;
    agg_kernel<<<blocks, threads, 0, stream>>>(
        nodes, neighs, embed, labels, distance, spectral,
        freq, dist_e, W1, b1, W2, b2, out);
}